// Round 1
// baseline (148.292 us; speedup 1.0000x reference)
//
#include <hip/hip_runtime.h>
#include <hip/hip_bf16.h>

// Gemma4AudioRelativePosition — fused bf16-MFMA implementation.
// out[b,h,n,s,c] = sum_d q[b,n,s,h,d]*keys[b,n,c,h,d]
//                + (0 <= c-s <= 127 ? sum_d q[b,n,s,h,d]*proj[c-s,h,d] : 0)
// proj[p,j] = sum_t sin_emb[p,t] * W_pos[j,t]  (128 x 512), stored bf16 in d_ws.

typedef __bf16 bf16x8 __attribute__((ext_vector_type(8)));
typedef unsigned short u16x8 __attribute__((ext_vector_type(8)));
typedef float f32x4 __attribute__((ext_vector_type(4)));

__device__ __forceinline__ unsigned short f2bf(float f) {
    unsigned u = __float_as_uint(f);
    u = (u + 0x7FFFu + ((u >> 16) & 1u)) >> 16;   // RNE
    return (unsigned short)u;
}
__device__ __forceinline__ float bf2f(unsigned short s) {
    return __uint_as_float(((unsigned)s) << 16);
}

// ---------------- kernel 1: proj = sin_emb @ W_pos^T  (bf16 out) ----------------
__global__ __launch_bounds__(256) void proj_kernel(const float* __restrict__ W,
                                                   unsigned short* __restrict__ projw) {
    __shared__ float se[512];
    int p = blockIdx.x;     // 0..127
    int t = threadIdx.x;    // 0..255
    const float LOGINC = (float)(9.210340371976184 / 255.0);  // ln(1e4)/255
    float pos = (float)(127 - p);
    float inv = expf(-LOGINC * (float)t);
    float ang = pos * inv;
    se[t]       = sinf(ang);
    se[t + 256] = cosf(ang);
    __syncthreads();
    const float4* se4 = (const float4*)se;
    const float4* w0  = (const float4*)(W + (size_t)t * 512);
    const float4* w1  = (const float4*)(W + (size_t)(t + 256) * 512);
    float a0 = 0.f, a1 = 0.f;
#pragma unroll 4
    for (int i = 0; i < 128; ++i) {
        float4 s4 = se4[i];
        float4 x  = w0[i];
        float4 y  = w1[i];
        a0 += s4.x * x.x + s4.y * x.y + s4.z * x.z + s4.w * x.w;
        a1 += s4.x * y.x + s4.y * y.y + s4.z * y.z + s4.w * y.w;
    }
    projw[p * 512 + t]       = f2bf(a0);
    projw[p * 512 + t + 256] = f2bf(a1);
}

// ---------------- kernel 2: fused AC + skewed BD ----------------
__global__ __launch_bounds__(256) void fused_kernel(const float* __restrict__ Q,
                                                    const float* __restrict__ Kg,
                                                    const unsigned short* __restrict__ projw,
                                                    float* __restrict__ out) {
    __shared__ unsigned short Klds[256 * 64];   // keys tile, bf16, XOR-swizzled
    __shared__ unsigned short BDs[128 * 128];   // BD[s][(s+p)&127], bf16, XOR-swizzled

    int idx = blockIdx.x;
    int n = idx & 63;
    int h = (idx >> 6) & 7;
    int b = idx >> 9;

    const float* qbase = Q  + ((size_t)(b * 64 + n) * 128) * 512 + h * 64;
    const float* kbase = Kg + ((size_t)(b * 64 + n) * 256) * 512 + h * 64;

    int tid = threadIdx.x;
    int w  = tid >> 6;     // wave 0..3 -> s-stripe [32w, 32w+32)
    int l  = tid & 63;
    int lo = l & 15;
    int hi = l >> 4;

    // ---- A-fragments: global fp32 -> reg bf16 (each q element read exactly once)
    bf16x8 afrag[2][2];
#pragma unroll
    for (int i2 = 0; i2 < 2; ++i2) {
        int row = w * 32 + i2 * 16 + lo;
        const float* ar = qbase + (size_t)row * 512;
#pragma unroll
        for (int kk = 0; kk < 2; ++kk) {
            float4 va = *(const float4*)(ar + kk * 32 + hi * 8);
            float4 vb = *(const float4*)(ar + kk * 32 + hi * 8 + 4);
            u16x8 u;
            u[0] = f2bf(va.x); u[1] = f2bf(va.y); u[2] = f2bf(va.z); u[3] = f2bf(va.w);
            u[4] = f2bf(vb.x); u[5] = f2bf(vb.y); u[6] = f2bf(vb.z); u[7] = f2bf(vb.w);
            afrag[i2][kk] = __builtin_bit_cast(bf16x8, u);
        }
    }

    // ---- Phase 1: BD = A @ P^T for this wave's 32 rows, store skewed bf16 in LDS.
    // Same wave writes & later reads its own rows -> no barrier needed for BDs.
    const unsigned short* pbase = projw + h * 64;
#pragma unroll 2
    for (int pj = 0; pj < 8; ++pj) {
        int prow = pj * 16 + lo;
        const unsigned short* pr = pbase + (size_t)prow * 512;
        bf16x8 pf0 = *(const bf16x8*)(pr + hi * 8);
        bf16x8 pf1 = *(const bf16x8*)(pr + 32 + hi * 8);
#pragma unroll
        for (int i2 = 0; i2 < 2; ++i2) {
            f32x4 acc = {0.f, 0.f, 0.f, 0.f};
            acc = __builtin_amdgcn_mfma_f32_16x16x32_bf16(afrag[i2][0], pf0, acc, 0, 0, 0);
            acc = __builtin_amdgcn_mfma_f32_16x16x32_bf16(afrag[i2][1], pf1, acc, 0, 0, 0);
            int sb = w * 32 + i2 * 16 + hi * 4;
            int p  = pj * 16 + lo;
#pragma unroll
            for (int jr = 0; jr < 4; ++jr) {
                int s  = sb + jr;
                int cw = (s + p) & 127;           // band is 128 wide -> mod-128 bijection
                BDs[s * 128 + (cw ^ ((s & 7) << 3))] = f2bf(acc[jr]);
            }
        }
    }

    // ---- stage keys: fp32 global -> bf16 LDS (swizzled)
    {
        int r4 = tid >> 2;   // 0..63
        int q4 = tid & 3;    // 0..3
#pragma unroll
        for (int it = 0; it < 4; ++it) {
            int row = it * 64 + r4;
            const float4* src = (const float4*)(kbase + (size_t)row * 512);
#pragma unroll
            for (int j = 0; j < 4; ++j) {
                int slot = q4 + 4 * j;            // 0..15 (float4 slot in the 64-float row)
                float4 v = src[slot];
                unsigned s0 = f2bf(v.x), s1 = f2bf(v.y), s2 = f2bf(v.z), s3 = f2bf(v.w);
                uint2 pk;
                pk.x = s0 | (s1 << 16);
                pk.y = s2 | (s3 << 16);
                int col = slot * 4;               // d index (multiple of 4)
                *reinterpret_cast<uint2*>(&Klds[row * 64 + (col ^ ((row & 7) << 3))]) = pk;
            }
        }
    }
    __syncthreads();

    // ---- Phase 2: AC tiles + banded BD epilogue + store
    size_t obase = ((size_t)((b * 8 + h) * 64 + n)) * (128 * 256);
#pragma unroll 2
    for (int cj = 0; cj < 16; ++cj) {
        int krow = cj * 16 + lo;
        bf16x8 kf0 = *(const bf16x8*)&Klds[krow * 64 + ((hi * 8)      ^ ((krow & 7) << 3))];
        bf16x8 kf1 = *(const bf16x8*)&Klds[krow * 64 + ((32 + hi * 8) ^ ((krow & 7) << 3))];
#pragma unroll
        for (int i2 = 0; i2 < 2; ++i2) {
            f32x4 acc = {0.f, 0.f, 0.f, 0.f};
            acc = __builtin_amdgcn_mfma_f32_16x16x32_bf16(afrag[i2][0], kf0, acc, 0, 0, 0);
            acc = __builtin_amdgcn_mfma_f32_16x16x32_bf16(afrag[i2][1], kf1, acc, 0, 0, 0);
            int stile = 2 * w + i2;
            int sb = stile * 16 + hi * 4;
            int c  = cj * 16 + lo;
            if (cj >= stile && cj <= stile + 8) {   // band-active tile (uniform branch)
#pragma unroll
                for (int jr = 0; jr < 4; ++jr) {
                    int s = sb + jr;
                    int p = c - s;
                    if ((unsigned)p < 128u) {
                        acc[jr] += bf2f(BDs[s * 128 + ((c & 127) ^ ((s & 7) << 3))]);
                    }
                }
            }
            float* orow = out + obase;
#pragma unroll
            for (int jr = 0; jr < 4; ++jr) {
                orow[(size_t)(sb + jr) * 256 + c] = acc[jr];
            }
        }
    }
}

extern "C" void kernel_launch(void* const* d_in, const int* in_sizes, int n_in,
                              void* d_out, int out_size, void* d_ws, size_t ws_size,
                              hipStream_t stream) {
    const float* Q  = (const float*)d_in[0];
    const float* Kg = (const float*)d_in[1];
    const float* W  = (const float*)d_in[2];
    float* out = (float*)d_out;
    unsigned short* projw = (unsigned short*)d_ws;   // 128*512 bf16 = 128 KB

    hipLaunchKernelGGL(proj_kernel, dim3(128), dim3(256), 0, stream, W, projw);
    hipLaunchKernelGGL(fused_kernel, dim3(2048), dim3(256), 0, stream, Q, Kg, projw, out);
}